// Round 9
// baseline (2350.489 us; speedup 1.0000x reference)
//
#include <hip/hip_runtime.h>

namespace {
constexpr int kB = 32;       // batch
constexpr int kN = 32768;    // num_primary
constexpr int kQ = 8;        // dim_primary
constexpr int kD = 10;       // num_digit
constexpr int kV = 16;       // dim_digit
constexpr int kRows = kB * kD;        // 320
constexpr int kThreads = 512;         // 8 waves; wave = bgrp (4 b); lane = dslot*4+vq
constexpr int kGrid = 1024;           // 4 blocks/CU (2048 thr/CU cap), 32 n/block
constexpr int kNPB = kN / kGrid;      // 32 n per block
}

template <int CTRL>
__device__ __forceinline__ float dpp_mv(float x) {
  return __int_as_float(__builtin_amdgcn_update_dpp(
      0, __float_as_int(x), CTRL, 0xF, 0xF, true));
}

// PHASE 0: c = 1/10 exactly (folded into final scale). PHASE 1: softmax(u_hat.vprev).
// No LDS, no barriers: W read directly from global (L1/L2 serve the 8x intra-block
// reuse); u via lane-distributed global loads + compile-time readlane.
template <int PHASE>
__launch_bounds__(kThreads, 8)   // 8 waves/EU -> 4 blocks/CU; VGPR budget 256
__global__ void routing_pass(const float* __restrict__ u,     // [B,N,Q]
                             const float* __restrict__ W,     // [D,N,V,Q]
                             const float* __restrict__ vprev, // [B,D,V]
                             float* __restrict__ s_out) {     // [B,D,V]
  const int t = threadIdx.x;
  const int ln = t & 63;
  const int dslot = ln >> 2;     // 0..15, active if <10
  const int vq = ln & 3;         // v-quarter; thread's v = j*4+vq
  const bool act = (dslot < kD);
  const int dd = act ? dslot : dslot - kD;  // idle lanes alias real d (same cache lines)
  const int b0 = (t >> 6) * 4;   // wave's b-group

  float vp[4][4];
  if constexpr (PHASE != 0) {
    #pragma unroll
    for (int bb = 0; bb < 4; ++bb)
      #pragma unroll
      for (int j = 0; j < 4; ++j)
        vp[bb][j] = vprev[((b0 + bb) * kD + dd) * kV + j * 4 + vq];
  }

  float acc[4][4];
  #pragma unroll
  for (int bb = 0; bb < 4; ++bb)
    #pragma unroll
    for (int j = 0; j < 4; ++j) acc[bb][j] = 0.0f;

  const int n_base = blockIdx.x * kNPB;
  // W base for this thread's d-slab (bytes); +512 per n.
  const char* wbase = (const char*)W + ((size_t)dd * kN + n_base) * 512 + vq * 32;
  // Lane-distributed u pickup: lane L carries u[b0+((L&31)>>3)][n0+pair*2+(L>>5)][L&7].
  const int ub = b0 + ((ln & 31) >> 3);
  const float* ubase = u + ((size_t)ub * kN + n_base + (ln >> 5)) * kQ + (ln & 7);

  for (int g = 0; g < kNPB / 4; ++g) {
    const float r0 = ubase[(g * 4 + 0) * kQ];   // n0+un
    const float r1 = ubase[(g * 4 + 2) * kQ];   // n0+2+un
    #pragma unroll
    for (int nl = 0; nl < 4; ++nl) {
      const float upair = (nl < 2) ? r0 : r1;
      const int hb = (nl & 1) * 32;  // compile-time under unroll
      const char* wn = wbase + (size_t)(g * 4 + nl) * 512;

      float uh[4][4];
      #pragma unroll
      for (int bb = 0; bb < 4; ++bb)
        #pragma unroll
        for (int j = 0; j < 4; ++j) uh[bb][j] = 0.0f;

      #pragma unroll
      for (int qh = 0; qh < 2; ++qh) {
        // u values via compile-time readlane (VALU; no DS, no scalar-mem)
        float us[4][4];
        #pragma unroll
        for (int bb = 0; bb < 4; ++bb)
          #pragma unroll
          for (int ql = 0; ql < 4; ++ql)
            us[bb][ql] = __int_as_float(__builtin_amdgcn_readlane(
                __float_as_int(upair), hb + bb * 8 + qh * 4 + ql));
        #pragma unroll
        for (int j = 0; j < 4; ++j) {
          // byte offset (j*4+vq)*32 + qh*16 (vq folded into wbase)
          const float4 w4 = *(const float4*)(wn + j * 128 + qh * 16);
          #pragma unroll
          for (int bb = 0; bb < 4; ++bb) {
            uh[bb][j] = fmaf(w4.x, us[bb][0], uh[bb][j]);
            uh[bb][j] = fmaf(w4.y, us[bb][1], uh[bb][j]);
            uh[bb][j] = fmaf(w4.z, us[bb][2], uh[bb][j]);
            uh[bb][j] = fmaf(w4.w, us[bb][3], uh[bb][j]);
          }
        }
      }
      if constexpr (PHASE != 0) {
        // logits for all 4 b (vq all-reduce via quad_perm DPP: xor1, xor2)
        float lg[4];
        #pragma unroll
        for (int bb = 0; bb < 4; ++bb) {
          float t0 = uh[bb][0] * vp[bb][0];
          t0 = fmaf(uh[bb][1], vp[bb][1], t0);
          t0 = fmaf(uh[bb][2], vp[bb][2], t0);
          t0 = fmaf(uh[bb][3], vp[bb][3], t0);
          t0 += dpp_mv<0xB1>(t0);
          t0 += dpp_mv<0x4E>(t0);
          lg[bb] = t0;
        }
        // each lane takes bb = vq -> ONE exp, ONE den-reduce, ONE rcp for all 4 b
        const float ta = (vq & 2) ? lg[2] : lg[0];
        const float tb = (vq & 2) ? lg[3] : lg[1];
        const float lsel = (vq & 1) ? tb : ta;
        const float esel = act ? __expf(lsel) : 0.0f;
        float den = esel;                 // sum over 16 dslots, vq preserved:
        den += dpp_mv<0x124>(den);        // row_ror:4
        den += dpp_mv<0x128>(den);        // row_ror:8
        den += __shfl_xor(den, 16);       // cross-row
        den += __shfl_xor(den, 32);       // cross-half
        const float csel = esel * __builtin_amdgcn_rcpf(den);
        // redistribute: quad_perm broadcast of each quad lane's c
        const float cb[4] = {dpp_mv<0x00>(csel), dpp_mv<0x55>(csel),
                             dpp_mv<0xAA>(csel), dpp_mv<0xFF>(csel)};
        #pragma unroll
        for (int bb = 0; bb < 4; ++bb)
          #pragma unroll
          for (int j = 0; j < 4; ++j)
            acc[bb][j] = fmaf(cb[bb], uh[bb][j], acc[bb][j]);
      } else {
        #pragma unroll
        for (int bb = 0; bb < 4; ++bb)
          #pragma unroll
          for (int j = 0; j < 4; ++j) acc[bb][j] += uh[bb][j];
      }
    }
  }

  if (act) {
    const float scale = (PHASE == 0) ? 0.1f : 1.0f;
    #pragma unroll
    for (int bb = 0; bb < 4; ++bb) {
      float* srow = s_out + ((b0 + bb) * kD + dslot) * kV + vq;
      #pragma unroll
      for (int j = 0; j < 4; ++j)
        atomicAdd(&srow[j * 4], acc[bb][j] * scale);
    }
  }
}

// squash per (b,d) row. MODE 0: vprev = squash(s); s = 0
//                       MODE 1: vprev += squash(s); s = 0
//                       MODE 2: out = squash(s)
template <int MODE>
__global__ void squash_kernel(float* __restrict__ s,
                              float* __restrict__ vprev,
                              float* __restrict__ out) {
  const int t = threadIdx.x;
  if (t >= kRows) return;
  float* sr = s + t * kV;
  float sv[kV];
  float n2 = 0.0f;
  #pragma unroll
  for (int v = 0; v < kV; ++v) {
    sv[v] = sr[v];
    n2 = fmaf(sv[v], sv[v], n2);
  }
  if (MODE != 2) {
    #pragma unroll
    for (int v = 0; v < kV; ++v) sr[v] = 0.0f;  // ready for next pass
  }
  const float norm = sqrtf(n2);
  const float coef = n2 / ((n2 + 1.0f) * (norm + 1e-7f));
  float* dst = (MODE == 2) ? (out + t * kV) : (vprev + t * kV);
  #pragma unroll
  for (int v = 0; v < kV; ++v) {
    float val = coef * sv[v];
    if (MODE == 1) val += dst[v];
    dst[v] = val;
  }
}

extern "C" void kernel_launch(void* const* d_in, const int* in_sizes, int n_in,
                              void* d_out, int out_size, void* d_ws, size_t ws_size,
                              hipStream_t stream) {
  const float* u = reinterpret_cast<const float*>(d_in[0]);  // primary_caps [B,N,Q]
  const float* W = reinterpret_cast<const float*>(d_in[1]);  // W [D,N,V,Q]
  float* out = reinterpret_cast<float*>(d_out);              // v [B,D,V] fp32

  float* s = reinterpret_cast<float*>(d_ws);   // [B,D,V] accumulator
  float* vprev = s + kRows * kV;               // [B,D,V] running v / vsum
  const size_t sbytes = (size_t)kRows * kV * sizeof(float);

  // r = 0: c uniform -> s0 = 0.1 * sum_n u_hat ; v0 = squash(s0)
  (void)hipMemsetAsync(s, 0, sbytes, stream);
  routing_pass<0><<<kGrid, kThreads, 0, stream>>>(u, W, nullptr, s);
  squash_kernel<0><<<1, kThreads, 0, stream>>>(s, vprev, out);

  // r = 1: logits = u_hat . v0 ; v1 = squash(s1) ; vprev = v0 + v1
  routing_pass<1><<<kGrid, kThreads, 0, stream>>>(u, W, vprev, s);
  squash_kernel<1><<<1, kThreads, 0, stream>>>(s, vprev, out);

  // r = 2: logits = u_hat . (v0+v1) ; out = squash(s2)
  routing_pass<1><<<kGrid, kThreads, 0, stream>>>(u, W, vprev, s);
  squash_kernel<2><<<1, kThreads, 0, stream>>>(s, vprev, out);
}

// Round 10
// 618.713 us; speedup vs baseline: 3.7990x; 3.7990x over previous
//
#include <hip/hip_runtime.h>

namespace {
constexpr int kB = 32;       // batch
constexpr int kN = 32768;    // num_primary
constexpr int kQ = 8;        // dim_primary
constexpr int kD = 10;       // num_digit
constexpr int kV = 16;       // dim_digit
constexpr int kRows = kB * kD;        // 320
constexpr int kThreads = 512;         // 8 waves; wave = bgrp (4 b); lane = dslot*4+vq
constexpr int kGrid = 1024;           // 32 n/block
constexpr int kNPB = kN / kGrid;      // 32 n per block
}

template <int CTRL>
__device__ __forceinline__ float dpp_mv(float x) {
  return __int_as_float(__builtin_amdgcn_update_dpp(
      0, __float_as_int(x), CTRL, 0xF, 0xF, true));
}

// PHASE 0: c = 1/10 exactly (folded into final scale). PHASE 1: softmax(u_hat.vprev).
// No LDS, no barriers: W read directly from global (L1/L2 serve the 8x intra-block
// reuse); u via lane-distributed global loads + compile-time readlane.
template <int PHASE>
__launch_bounds__(kThreads, 2)   // empirical: VGPR cap = 256/arg -> 128; demand ~96
__global__ void routing_pass(const float* __restrict__ u,     // [B,N,Q]
                             const float* __restrict__ W,     // [D,N,V,Q]
                             const float* __restrict__ vprev, // [B,D,V]
                             float* __restrict__ s_out) {     // [B,D,V]
  const int t = threadIdx.x;
  const int ln = t & 63;
  const int dslot = ln >> 2;     // 0..15, active if <10
  const int vq = ln & 3;         // v-quarter; thread's v = j*4+vq
  const bool act = (dslot < kD);
  const int dd = act ? dslot : dslot - kD;  // idle lanes alias real d (same cache lines)
  const int b0 = (t >> 6) * 4;   // wave's b-group

  float vp[4][4];
  if constexpr (PHASE != 0) {
    #pragma unroll
    for (int bb = 0; bb < 4; ++bb)
      #pragma unroll
      for (int j = 0; j < 4; ++j)
        vp[bb][j] = vprev[((b0 + bb) * kD + dd) * kV + j * 4 + vq];
  }

  float acc[4][4];
  #pragma unroll
  for (int bb = 0; bb < 4; ++bb)
    #pragma unroll
    for (int j = 0; j < 4; ++j) acc[bb][j] = 0.0f;

  const int n_base = blockIdx.x * kNPB;
  // W base for this thread's d-slab (bytes); +512 per n.
  const char* wbase = (const char*)W + ((size_t)dd * kN + n_base) * 512 + vq * 32;
  // Lane-distributed u pickup: lane L carries u[b0+((L&31)>>3)][n0+pair*2+(L>>5)][L&7].
  const int ub = b0 + ((ln & 31) >> 3);
  const float* ubase = u + ((size_t)ub * kN + n_base + (ln >> 5)) * kQ + (ln & 7);

  for (int g = 0; g < kNPB / 4; ++g) {
    const float r0 = ubase[(g * 4 + 0) * kQ];   // n0+un
    const float r1 = ubase[(g * 4 + 2) * kQ];   // n0+2+un
    #pragma unroll
    for (int nl = 0; nl < 4; ++nl) {
      const float upair = (nl < 2) ? r0 : r1;
      const int hb = (nl & 1) * 32;  // compile-time under unroll
      const char* wn = wbase + (size_t)(g * 4 + nl) * 512;

      float uh[4][4];
      #pragma unroll
      for (int bb = 0; bb < 4; ++bb)
        #pragma unroll
        for (int j = 0; j < 4; ++j) uh[bb][j] = 0.0f;

      #pragma unroll
      for (int qh = 0; qh < 2; ++qh) {
        // u values via compile-time readlane (VALU; no DS, no scalar-mem)
        float us[4][4];
        #pragma unroll
        for (int bb = 0; bb < 4; ++bb)
          #pragma unroll
          for (int ql = 0; ql < 4; ++ql)
            us[bb][ql] = __int_as_float(__builtin_amdgcn_readlane(
                __float_as_int(upair), hb + bb * 8 + qh * 4 + ql));
        #pragma unroll
        for (int j = 0; j < 4; ++j) {
          // byte offset (j*4+vq)*32 + qh*16 (vq folded into wbase)
          const float4 w4 = *(const float4*)(wn + j * 128 + qh * 16);
          #pragma unroll
          for (int bb = 0; bb < 4; ++bb) {
            uh[bb][j] = fmaf(w4.x, us[bb][0], uh[bb][j]);
            uh[bb][j] = fmaf(w4.y, us[bb][1], uh[bb][j]);
            uh[bb][j] = fmaf(w4.z, us[bb][2], uh[bb][j]);
            uh[bb][j] = fmaf(w4.w, us[bb][3], uh[bb][j]);
          }
        }
      }
      if constexpr (PHASE != 0) {
        // logits for all 4 b (vq all-reduce via quad_perm DPP: xor1, xor2)
        float lg[4];
        #pragma unroll
        for (int bb = 0; bb < 4; ++bb) {
          float t0 = uh[bb][0] * vp[bb][0];
          t0 = fmaf(uh[bb][1], vp[bb][1], t0);
          t0 = fmaf(uh[bb][2], vp[bb][2], t0);
          t0 = fmaf(uh[bb][3], vp[bb][3], t0);
          t0 += dpp_mv<0xB1>(t0);
          t0 += dpp_mv<0x4E>(t0);
          lg[bb] = t0;
        }
        // each lane takes bb = vq -> ONE exp, ONE den-reduce, ONE rcp for all 4 b
        const float ta = (vq & 2) ? lg[2] : lg[0];
        const float tb = (vq & 2) ? lg[3] : lg[1];
        const float lsel = (vq & 1) ? tb : ta;
        const float esel = act ? __expf(lsel) : 0.0f;
        float den = esel;                 // sum over 16 dslots, vq preserved:
        den += dpp_mv<0x124>(den);        // row_ror:4
        den += dpp_mv<0x128>(den);        // row_ror:8
        den += __shfl_xor(den, 16);       // cross-row
        den += __shfl_xor(den, 32);       // cross-half
        const float csel = esel * __builtin_amdgcn_rcpf(den);
        // redistribute: quad_perm broadcast of each quad lane's c
        const float cb[4] = {dpp_mv<0x00>(csel), dpp_mv<0x55>(csel),
                             dpp_mv<0xAA>(csel), dpp_mv<0xFF>(csel)};
        #pragma unroll
        for (int bb = 0; bb < 4; ++bb)
          #pragma unroll
          for (int j = 0; j < 4; ++j)
            acc[bb][j] = fmaf(cb[bb], uh[bb][j], acc[bb][j]);
      } else {
        #pragma unroll
        for (int bb = 0; bb < 4; ++bb)
          #pragma unroll
          for (int j = 0; j < 4; ++j) acc[bb][j] += uh[bb][j];
      }
    }
  }

  if (act) {
    const float scale = (PHASE == 0) ? 0.1f : 1.0f;
    #pragma unroll
    for (int bb = 0; bb < 4; ++bb) {
      float* srow = s_out + ((b0 + bb) * kD + dslot) * kV + vq;
      #pragma unroll
      for (int j = 0; j < 4; ++j)
        atomicAdd(&srow[j * 4], acc[bb][j] * scale);
    }
  }
}

// squash per (b,d) row. MODE 0: vprev = squash(s); s = 0
//                       MODE 1: vprev += squash(s); s = 0
//                       MODE 2: out = squash(s)
template <int MODE>
__global__ void squash_kernel(float* __restrict__ s,
                              float* __restrict__ vprev,
                              float* __restrict__ out) {
  const int t = threadIdx.x;
  if (t >= kRows) return;
  float* sr = s + t * kV;
  float sv[kV];
  float n2 = 0.0f;
  #pragma unroll
  for (int v = 0; v < kV; ++v) {
    sv[v] = sr[v];
    n2 = fmaf(sv[v], sv[v], n2);
  }
  if (MODE != 2) {
    #pragma unroll
    for (int v = 0; v < kV; ++v) sr[v] = 0.0f;  // ready for next pass
  }
  const float norm = sqrtf(n2);
  const float coef = n2 / ((n2 + 1.0f) * (norm + 1e-7f));
  float* dst = (MODE == 2) ? (out + t * kV) : (vprev + t * kV);
  #pragma unroll
  for (int v = 0; v < kV; ++v) {
    float val = coef * sv[v];
    if (MODE == 1) val += dst[v];
    dst[v] = val;
  }
}

extern "C" void kernel_launch(void* const* d_in, const int* in_sizes, int n_in,
                              void* d_out, int out_size, void* d_ws, size_t ws_size,
                              hipStream_t stream) {
  const float* u = reinterpret_cast<const float*>(d_in[0]);  // primary_caps [B,N,Q]
  const float* W = reinterpret_cast<const float*>(d_in[1]);  // W [D,N,V,Q]
  float* out = reinterpret_cast<float*>(d_out);              // v [B,D,V] fp32

  float* s = reinterpret_cast<float*>(d_ws);   // [B,D,V] accumulator
  float* vprev = s + kRows * kV;               // [B,D,V] running v / vsum
  const size_t sbytes = (size_t)kRows * kV * sizeof(float);

  // r = 0: c uniform -> s0 = 0.1 * sum_n u_hat ; v0 = squash(s0)
  (void)hipMemsetAsync(s, 0, sbytes, stream);
  routing_pass<0><<<kGrid, kThreads, 0, stream>>>(u, W, nullptr, s);
  squash_kernel<0><<<1, kThreads, 0, stream>>>(s, vprev, out);

  // r = 1: logits = u_hat . v0 ; v1 = squash(s1) ; vprev = v0 + v1
  routing_pass<1><<<kGrid, kThreads, 0, stream>>>(u, W, vprev, s);
  squash_kernel<1><<<1, kThreads, 0, stream>>>(s, vprev, out);

  // r = 2: logits = u_hat . (v0+v1) ; out = squash(s2)
  routing_pass<1><<<kGrid, kThreads, 0, stream>>>(u, W, vprev, s);
  squash_kernel<2><<<1, kThreads, 0, stream>>>(s, vprev, out);
}

// Round 11
// 608.509 us; speedup vs baseline: 3.8627x; 1.0168x over previous
//
#include <hip/hip_runtime.h>

namespace {
constexpr int kB = 32;       // batch
constexpr int kN = 32768;    // num_primary
constexpr int kQ = 8;        // dim_primary
constexpr int kD = 10;       // num_digit
constexpr int kV = 16;       // dim_digit
constexpr int kRows = kB * kD;        // 320
constexpr int kThreads = 512;         // 8 waves; wave = bgrp (4 b); lane = dslot*4+vq
constexpr int kGrid = 1024;           // 32 n/block
constexpr int kNPB = kN / kGrid;      // 32 n per block
constexpr int kG = kNPB / 4;          // 8 groups of 4 n
}

template <int CTRL>
__device__ __forceinline__ float dpp_mv(float x) {
  return __int_as_float(__builtin_amdgcn_update_dpp(
      0, __float_as_int(x), CTRL, 0xF, 0xF, true));
}

// Load the 8 W-float4s for one n into a named register buffer (static idx).
#define LOAD8(WBUF, NN)                                                   \
  do {                                                                    \
    const char* wn_ = wbase + (size_t)(NN)*512;                           \
    _Pragma("unroll")                                                     \
    for (int i2 = 0; i2 < 8; ++i2)                                        \
      WBUF[i2] = *(const float4*)(wn_ + (i2 & 3) * 128 + (i2 >> 2) * 16); \
  } while (0)

// Compute one n from register buffer WBUF; u values from lanes HB..HB+31 of UPAIR.
#define COMPUTE_N(WBUF, UPAIR, HB)                                            \
  do {                                                                        \
    float uh[4][4];                                                           \
    _Pragma("unroll") for (int bb = 0; bb < 4; ++bb)                          \
        _Pragma("unroll") for (int j = 0; j < 4; ++j) uh[bb][j] = 0.0f;       \
    _Pragma("unroll") for (int qh = 0; qh < 2; ++qh) {                        \
      float us[4][4];                                                         \
      _Pragma("unroll") for (int bb = 0; bb < 4; ++bb)                        \
          _Pragma("unroll") for (int ql = 0; ql < 4; ++ql)                    \
              us[bb][ql] = __int_as_float(__builtin_amdgcn_readlane(          \
                  __float_as_int(UPAIR), (HB) + bb * 8 + qh * 4 + ql));       \
      _Pragma("unroll") for (int j = 0; j < 4; ++j) {                         \
        const float4 w4 = WBUF[qh * 4 + j];                                   \
        _Pragma("unroll") for (int bb = 0; bb < 4; ++bb) {                    \
          uh[bb][j] = fmaf(w4.x, us[bb][0], uh[bb][j]);                       \
          uh[bb][j] = fmaf(w4.y, us[bb][1], uh[bb][j]);                       \
          uh[bb][j] = fmaf(w4.z, us[bb][2], uh[bb][j]);                       \
          uh[bb][j] = fmaf(w4.w, us[bb][3], uh[bb][j]);                       \
        }                                                                     \
      }                                                                       \
    }                                                                         \
    if constexpr (PHASE != 0) {                                               \
      float lg[4];                                                            \
      _Pragma("unroll") for (int bb = 0; bb < 4; ++bb) {                      \
        float t0 = uh[bb][0] * vp[bb][0];                                     \
        t0 = fmaf(uh[bb][1], vp[bb][1], t0);                                  \
        t0 = fmaf(uh[bb][2], vp[bb][2], t0);                                  \
        t0 = fmaf(uh[bb][3], vp[bb][3], t0);                                  \
        t0 += dpp_mv<0xB1>(t0);                                               \
        t0 += dpp_mv<0x4E>(t0);                                               \
        lg[bb] = t0;                                                          \
      }                                                                       \
      const float ta = (vq & 2) ? lg[2] : lg[0];                              \
      const float tb = (vq & 2) ? lg[3] : lg[1];                              \
      const float lsel = (vq & 1) ? tb : ta;                                  \
      const float esel = act ? __expf(lsel) : 0.0f;                           \
      float den = esel;                                                       \
      den += dpp_mv<0x124>(den);                                              \
      den += dpp_mv<0x128>(den);                                              \
      den += __shfl_xor(den, 16);                                             \
      den += __shfl_xor(den, 32);                                             \
      const float csel = esel * __builtin_amdgcn_rcpf(den);                   \
      const float cb0 = dpp_mv<0x00>(csel), cb1 = dpp_mv<0x55>(csel);         \
      const float cb2 = dpp_mv<0xAA>(csel), cb3 = dpp_mv<0xFF>(csel);         \
      _Pragma("unroll") for (int j = 0; j < 4; ++j) {                         \
        acc[0][j] = fmaf(cb0, uh[0][j], acc[0][j]);                           \
        acc[1][j] = fmaf(cb1, uh[1][j], acc[1][j]);                           \
        acc[2][j] = fmaf(cb2, uh[2][j], acc[2][j]);                           \
        acc[3][j] = fmaf(cb3, uh[3][j], acc[3][j]);                           \
      }                                                                       \
    } else {                                                                  \
      _Pragma("unroll") for (int bb = 0; bb < 4; ++bb)                        \
          _Pragma("unroll") for (int j = 0; j < 4; ++j)                       \
              acc[bb][j] += uh[bb][j];                                        \
    }                                                                         \
  } while (0)

// PHASE 0: c = 1/10 exactly (folded into final scale). PHASE 1: softmax(u_hat.vprev).
// No LDS, no barriers. W direct from global (L1 serves the 8x intra-block reuse)
// with a 1-deep register prefetch pipeline; u lane-distributed + readlane.
template <int PHASE>
__launch_bounds__(kThreads)   // no waves/EU cap: residency set by actual VGPR use
__global__ void routing_pass(const float* __restrict__ u,     // [B,N,Q]
                             const float* __restrict__ W,     // [D,N,V,Q]
                             const float* __restrict__ vprev, // [B,D,V]
                             float* __restrict__ s_out) {     // [B,D,V]
  const int t = threadIdx.x;
  const int ln = t & 63;
  const int dslot = ln >> 2;     // 0..15, active if <10
  const int vq = ln & 3;         // v-quarter; thread's v = j*4+vq
  const bool act = (dslot < kD);
  const int dd = act ? dslot : dslot - kD;  // idle lanes alias real d (same cache lines)
  const int b0 = (t >> 6) * 4;   // wave's b-group

  float vp[4][4];
  if constexpr (PHASE != 0) {
    #pragma unroll
    for (int bb = 0; bb < 4; ++bb)
      #pragma unroll
      for (int j = 0; j < 4; ++j)
        vp[bb][j] = vprev[((b0 + bb) * kD + dd) * kV + j * 4 + vq];
  }

  float acc[4][4];
  #pragma unroll
  for (int bb = 0; bb < 4; ++bb)
    #pragma unroll
    for (int j = 0; j < 4; ++j) acc[bb][j] = 0.0f;

  const int n_base = blockIdx.x * kNPB;
  // W base for this thread's d-slab (bytes); +512 per n (vq folded in).
  const char* wbase = (const char*)W + ((size_t)dd * kN + n_base) * 512 + vq * 32;
  // Lane-distributed u pickup: lane L carries u[b0+((L&31)>>3)][n0+2g+(L>>5)][L&7].
  const int ub = b0 + ((ln & 31) >> 3);
  const float* ubase = u + ((size_t)ub * kN + n_base + (ln >> 5)) * kQ + (ln & 7);

  float4 wA[8], wB[8];
  LOAD8(wA, 0);                       // prologue: n-local 0
  float r0 = ubase[0 * kQ];           // g=0 u pair (n 0/1)
  float r1 = ubase[2 * kQ];           // g=0 u pair (n 2/3)

  for (int g = 0; g < kG; ++g) {
    const int nb = g * 4;
    const int gn = (g + 1 < kG) ? g + 1 : 0;      // clamped (harmless re-read)
    const float nr0 = ubase[(gn * 4 + 0) * kQ];   // prefetch next g's u
    const float nr1 = ubase[(gn * 4 + 2) * kQ];

    LOAD8(wB, nb + 1);
    COMPUTE_N(wA, r0, 0);
    LOAD8(wA, nb + 2);
    COMPUTE_N(wB, r0, 32);
    LOAD8(wB, nb + 3);
    COMPUTE_N(wA, r1, 0);
    LOAD8(wA, (g + 1 < kG) ? nb + 4 : 0);         // next g's first n (invariant)
    COMPUTE_N(wB, r1, 32);

    r0 = nr0;
    r1 = nr1;
  }

  if (act) {
    const float scale = (PHASE == 0) ? 0.1f : 1.0f;
    #pragma unroll
    for (int bb = 0; bb < 4; ++bb) {
      float* srow = s_out + ((b0 + bb) * kD + dslot) * kV + vq;
      #pragma unroll
      for (int j = 0; j < 4; ++j)
        atomicAdd(&srow[j * 4], acc[bb][j] * scale);
    }
  }
}

// squash per (b,d) row. MODE 0: vprev = squash(s); s = 0
//                       MODE 1: vprev += squash(s); s = 0
//                       MODE 2: out = squash(s)
template <int MODE>
__global__ void squash_kernel(float* __restrict__ s,
                              float* __restrict__ vprev,
                              float* __restrict__ out) {
  const int t = threadIdx.x;
  if (t >= kRows) return;
  float* sr = s + t * kV;
  float sv[kV];
  float n2 = 0.0f;
  #pragma unroll
  for (int v = 0; v < kV; ++v) {
    sv[v] = sr[v];
    n2 = fmaf(sv[v], sv[v], n2);
  }
  if (MODE != 2) {
    #pragma unroll
    for (int v = 0; v < kV; ++v) sr[v] = 0.0f;  // ready for next pass
  }
  const float norm = sqrtf(n2);
  const float coef = n2 / ((n2 + 1.0f) * (norm + 1e-7f));
  float* dst = (MODE == 2) ? (out + t * kV) : (vprev + t * kV);
  #pragma unroll
  for (int v = 0; v < kV; ++v) {
    float val = coef * sv[v];
    if (MODE == 1) val += dst[v];
    dst[v] = val;
  }
}

extern "C" void kernel_launch(void* const* d_in, const int* in_sizes, int n_in,
                              void* d_out, int out_size, void* d_ws, size_t ws_size,
                              hipStream_t stream) {
  const float* u = reinterpret_cast<const float*>(d_in[0]);  // primary_caps [B,N,Q]
  const float* W = reinterpret_cast<const float*>(d_in[1]);  // W [D,N,V,Q]
  float* out = reinterpret_cast<float*>(d_out);              // v [B,D,V] fp32

  float* s = reinterpret_cast<float*>(d_ws);   // [B,D,V] accumulator
  float* vprev = s + kRows * kV;               // [B,D,V] running v / vsum
  const size_t sbytes = (size_t)kRows * kV * sizeof(float);

  // r = 0: c uniform -> s0 = 0.1 * sum_n u_hat ; v0 = squash(s0)
  (void)hipMemsetAsync(s, 0, sbytes, stream);
  routing_pass<0><<<kGrid, kThreads, 0, stream>>>(u, W, nullptr, s);
  squash_kernel<0><<<1, kThreads, 0, stream>>>(s, vprev, out);

  // r = 1: logits = u_hat . v0 ; v1 = squash(s1) ; vprev = v0 + v1
  routing_pass<1><<<kGrid, kThreads, 0, stream>>>(u, W, vprev, s);
  squash_kernel<1><<<1, kThreads, 0, stream>>>(s, vprev, out);

  // r = 2: logits = u_hat . (v0+v1) ; out = squash(s2)
  routing_pass<1><<<kGrid, kThreads, 0, stream>>>(u, W, vprev, s);
  squash_kernel<2><<<1, kThreads, 0, stream>>>(s, vprev, out);
}